// Round 6
// baseline (271.407 us; speedup 1.0000x reference)
//
#include <hip/hip_runtime.h>

// ---------------- problem constants (from reference setup_inputs) ----------
#define DIMM   1536
#define NHEAD  12
#define HD     128
#define SEQ    2080      // F*H*W = 4*20*26
#define SPADN  2176      // ceil(SEQ/128)*128
#define HWPROD 520       // H*W
#define SCALE  0.08838834764831845f      // 1/sqrt(128)
#define K2F    0.12751744154f            // SCALE * log2(e)

typedef short short8  __attribute__((ext_vector_type(8)));   // 8 bf16 in 4 VGPRs
typedef float floatx4 __attribute__((ext_vector_type(4)));

__device__ __forceinline__ unsigned short f2bf(float f) {
    union { float f; unsigned u; } v; v.f = f;
    return (unsigned short)((v.u + 0x7fffu + ((v.u >> 16) & 1u)) >> 16);  // RNE
}
__device__ __forceinline__ float bf2f(unsigned short u) {
    union { unsigned u; float f; } v; v.u = ((unsigned)u) << 16;
    return v.f;
}

// async global->LDS, 16B per lane; LDS dest = wave-uniform base + lane*16
__device__ __forceinline__ void gld_lds16(const void* g, void* l) {
    __builtin_amdgcn_global_load_lds(
        (const __attribute__((address_space(1))) unsigned int*)g,
        (__attribute__((address_space(3))) unsigned int*)l, 16, 0, 0);
}

// q128 tiles: j=0..16, nkb(j)=min(2j+2,33), nchunks=ceil(nkb/8)
// prefix sum of nchunks:
__constant__ int c_base2[17] = {0,1,2,3,4,6,8,10,12,15,18,21,24,28,32,36,40};
#define SLOTS2_PER_HEAD 45

// ---------------- prep: x->bf16 (z=4) + 4 weight transposes (z=0..3) -------
__global__ void k_prep(const float* __restrict__ x,
                       const float* __restrict__ w0, const float* __restrict__ w1,
                       const float* __restrict__ w2, const float* __restrict__ w3,
                       unsigned short* __restrict__ xb,
                       unsigned short* __restrict__ t0, unsigned short* __restrict__ t1,
                       unsigned short* __restrict__ t2, unsigned short* __restrict__ t3) {
    int z = blockIdx.z;
    if (z == 4) {                       // cvt x: 2080*1536/4 float4 groups
        int n4 = SEQ * DIMM / 4;
        int idx = (blockIdx.y * 24 + blockIdx.x) * 256 + threadIdx.x;
#pragma unroll
        for (int i = 0; i < 6; i++) {
            int p = idx + i * 147456;
            if (p < n4) {
                float4 v = ((const float4*)x)[p];
                ushort4 o;
                o.x = f2bf(v.x); o.y = f2bf(v.y); o.z = f2bf(v.z); o.w = f2bf(v.w);
                ((ushort4*)xb)[p] = o;
            }
        }
        return;
    }
    const float* in = (z == 0) ? w0 : (z == 1) ? w1 : (z == 2) ? w2 : w3;
    unsigned short* out = (z == 0) ? t0 : (z == 1) ? t1 : (z == 2) ? t2 : t3;
    __shared__ float tile[64][65];
    int tx = threadIdx.x & 63, ty = threadIdx.x >> 6;
    int r0 = blockIdx.x * 64, c0 = blockIdx.y * 64;
#pragma unroll
    for (int i = 0; i < 16; i++)
        tile[i * 4 + ty][tx] = in[(size_t)(r0 + i * 4 + ty) * DIMM + c0 + tx];
    __syncthreads();
#pragma unroll
    for (int i = 0; i < 16; i++) {
        int cc = i * 4 + ty;
        out[(size_t)(c0 + cc) * DIMM + r0 + tx] = f2bf(tile[tx][cc]);
    }
}

// ---------------- QKV GEMM: bf16 out, fused layouts ------------------------
// 128x128 tile, BK=64, global_load_lds staging, xor-swizzled unpadded LDS.
// z=0 -> Qh bf16 [s][1536]; z=1 -> Kh bf16 [s][1536];
// z=2 -> Vt bf16 [1536][SPADN] (transposed store, pad cols left untouched).
__global__ __launch_bounds__(256, 3) void k_gemm(
    const unsigned short* __restrict__ A,
    const unsigned short* __restrict__ B0, const unsigned short* __restrict__ B1,
    const unsigned short* __restrict__ B2,
    const float* __restrict__ bias0, const float* __restrict__ bias1, const float* __restrict__ bias2,
    unsigned short* __restrict__ Qh, unsigned short* __restrict__ Kh,
    unsigned short* __restrict__ Vt,
    int M, int N, int K) {
    const unsigned short* B = B0; const float* bias = bias0;
    if (blockIdx.z == 1) { B = B1; bias = bias1; }
    if (blockIdx.z == 2) { B = B2; bias = bias2; }

    __shared__ unsigned short As[128 * 64];
    __shared__ unsigned short Bs[128 * 64];

    int tid = threadIdx.x;
    int lane = tid & 63, wv = tid >> 6;
    int quad = lane >> 4, l16 = lane & 15;
    int m0 = blockIdx.y * 128, n0 = blockIdx.x * 128;
    int wm = (wv >> 1) * 64, wn = (wv & 1) * 64;
    int sw = l16 & 7;

    int srow_in_blk = lane >> 3;
    int schunk = lane & 7;
    int gchunk = schunk ^ (srow_in_blk & 7);

    floatx4 acc[4][4];
#pragma unroll
    for (int i = 0; i < 4; i++)
#pragma unroll
        for (int j = 0; j < 4; j++) acc[i][j] = (floatx4){0.f, 0.f, 0.f, 0.f};

    for (int k0 = 0; k0 < K; k0 += 64) {
#pragma unroll
        for (int i = 0; i < 4; i++) {
            int blkrow = (wv * 4 + i) * 8;
            int r = blkrow + srow_in_blk;
            int ra = m0 + r; if (ra > M - 1) ra = M - 1;
            gld_lds16(A + (size_t)ra * K + k0 + gchunk * 8, &As[blkrow * 64]);
            gld_lds16(B + (size_t)(n0 + r) * K + k0 + gchunk * 8, &Bs[blkrow * 64]);
        }
        __syncthreads();
#pragma unroll
        for (int kc = 0; kc < 2; kc++) {
            short8 af[4], bfr[4];
#pragma unroll
            for (int t = 0; t < 4; t++) {
                int ca = ((kc * 4 + quad) ^ sw) << 3;
                af[t]  = *(const short8*)&As[(wm + t * 16 + l16) * 64 + ca];
                bfr[t] = *(const short8*)&Bs[(wn + t * 16 + l16) * 64 + ca];
            }
#pragma unroll
            for (int mi = 0; mi < 4; mi++)
#pragma unroll
                for (int ni = 0; ni < 4; ni++)
                    acc[mi][ni] = __builtin_amdgcn_mfma_f32_16x16x32_bf16(af[mi], bfr[ni], acc[mi][ni], 0, 0, 0);
        }
        __syncthreads();
    }
    // epilogue: C/D layout col=lane&15, row=quad*4+reg
    if (blockIdx.z == 2) {
        // Vt[d][q] transposed: rows r=0..3 are contiguous q indices per lane
#pragma unroll
        for (int mi = 0; mi < 4; mi++) {
            int row0 = m0 + wm + mi * 16 + quad * 4;
            if (row0 < M) {
#pragma unroll
                for (int ni = 0; ni < 4; ni++) {
                    int col = n0 + wn + ni * 16 + l16;
                    float b = bias[col];
                    ushort4 o;
                    o.x = f2bf(acc[mi][ni][0] + b);
                    o.y = f2bf(acc[mi][ni][1] + b);
                    o.z = f2bf(acc[mi][ni][2] + b);
                    o.w = f2bf(acc[mi][ni][3] + b);
                    *(ushort4*)(Vt + (size_t)col * SPADN + row0) = o;
                }
            }
        }
    } else {
        unsigned short* O = (blockIdx.z == 0) ? Qh : Kh;
#pragma unroll
        for (int mi = 0; mi < 4; mi++) {
#pragma unroll
            for (int r = 0; r < 4; r++) {
                int row = m0 + wm + mi * 16 + quad * 4 + r;
                if (row < M) {
#pragma unroll
                    for (int ni = 0; ni < 4; ni++) {
                        int col = n0 + wn + ni * 16 + l16;
                        O[(size_t)row * DIMM + col] = f2bf(acc[mi][ni][r] + bias[col]);
                    }
                }
            }
        }
    }
}

// ---------------- 64x64-tile GEMM for the output projection ---------------
__global__ __launch_bounds__(256, 8) void k_gemm64(
    const unsigned short* __restrict__ A, const unsigned short* __restrict__ B,
    const float* __restrict__ bias, float* __restrict__ C, int M, int N, int K) {
    __shared__ unsigned short As[64 * 64];
    __shared__ unsigned short Bs[64 * 64];
    int tid = threadIdx.x;
    int lane = tid & 63, wv = tid >> 6;
    int quad = lane >> 4, l16 = lane & 15;
    int m0 = blockIdx.y * 64, n0 = blockIdx.x * 64;
    int wm = (wv >> 1) * 32, wn = (wv & 1) * 32;

    int srow = lane >> 3;       // 0..7 rows per wave-call
    int schunk = lane & 7;

    floatx4 acc[2][2];
#pragma unroll
    for (int i = 0; i < 2; i++)
#pragma unroll
        for (int j = 0; j < 2; j++) acc[i][j] = (floatx4){0.f, 0.f, 0.f, 0.f};

    for (int k0 = 0; k0 < K; k0 += 64) {
#pragma unroll
        for (int i = 0; i < 2; i++) {
            int rb = (i * 4 + wv) * 8;            // wave-uniform row base
            int r = rb + srow;
            int g = schunk ^ (r & 7);
            int ra = m0 + r; if (ra > M - 1) ra = M - 1;
            gld_lds16(A + (size_t)ra * K + k0 + g * 8, &As[rb * 64]);
            gld_lds16(B + (size_t)(n0 + r) * K + k0 + g * 8, &Bs[rb * 64]);
        }
        __syncthreads();
#pragma unroll
        for (int kc = 0; kc < 2; kc++) {
            short8 af[2], bfr[2];
#pragma unroll
            for (int t = 0; t < 2; t++) {
                int rowa = wm + t * 16 + l16;
                int rowb = wn + t * 16 + l16;
                int c = kc * 4 + quad;
                af[t]  = *(const short8*)&As[rowa * 64 + ((c ^ (rowa & 7)) << 3)];
                bfr[t] = *(const short8*)&Bs[rowb * 64 + ((c ^ (rowb & 7)) << 3)];
            }
#pragma unroll
            for (int mi = 0; mi < 2; mi++)
#pragma unroll
                for (int ni = 0; ni < 2; ni++)
                    acc[mi][ni] = __builtin_amdgcn_mfma_f32_16x16x32_bf16(af[mi], bfr[ni], acc[mi][ni], 0, 0, 0);
        }
        __syncthreads();
    }
#pragma unroll
    for (int mi = 0; mi < 2; mi++) {
#pragma unroll
        for (int r = 0; r < 4; r++) {
            int row = m0 + wm + mi * 16 + quad * 4 + r;
            if (row < M) {
#pragma unroll
                for (int ni = 0; ni < 2; ni++) {
                    int col = n0 + wn + ni * 16 + l16;
                    C[(size_t)row * N + col] = acc[mi][ni][r] + bias[col];
                }
            }
        }
    }
}

// ---------------- RMSNorm(1536) + RoPE (bf16 in), write bf16 [h][s][d] -----
__global__ void k_rmsrope(const unsigned short* __restrict__ Qh, const unsigned short* __restrict__ Kh,
                          const float* __restrict__ gq, const float* __restrict__ gk,
                          const float* __restrict__ freqs,
                          unsigned short* __restrict__ Qa, unsigned short* __restrict__ Ka) {
    __shared__ float redq[4], redk[4];
    int s = blockIdx.x;
    int tid = threadIdx.x;
    int lane = tid & 63, wv = tid >> 6;
    const ushort2* qrow = (const ushort2*)(Qh + (size_t)s * DIMM);
    const ushort2* krow = (const ushort2*)(Kh + (size_t)s * DIMM);
    const float2* g2q = (const float2*)gq;
    const float2* g2k = (const float2*)gk;

    float2 qv[3], kv[3];
    float sq = 0.f, sk = 0.f;
#pragma unroll
    for (int j = 0; j < 3; j++) {
        int p = tid + j * 256;
        ushort2 uq = qrow[p], uk = krow[p];
        qv[j].x = bf2f(uq.x); qv[j].y = bf2f(uq.y);
        kv[j].x = bf2f(uk.x); kv[j].y = bf2f(uk.y);
        sq += qv[j].x * qv[j].x + qv[j].y * qv[j].y;
        sk += kv[j].x * kv[j].x + kv[j].y * kv[j].y;
    }
#pragma unroll
    for (int m = 32; m >= 1; m >>= 1) { sq += __shfl_xor(sq, m); sk += __shfl_xor(sk, m); }
    if (lane == 0) { redq[wv] = sq; redk[wv] = sk; }
    __syncthreads();
    float tq = redq[0] + redq[1] + redq[2] + redq[3];
    float tk = redk[0] + redk[1] + redk[2] + redk[3];
    float scq = rsqrtf(tq * (1.f / DIMM) + 1e-6f);
    float sck = rsqrtf(tk * (1.f / DIMM) + 1e-6f);

    int fi = s / HWPROD;
    int rem = s - fi * HWPROD;
    int hi = rem / 26;
    int wi = rem - hi * 26;
#pragma unroll
    for (int j = 0; j < 3; j++) {
        int p = tid + j * 256;
        int c = p & 63;
        int pos = (c < 22) ? fi : ((c < 43) ? hi : wi);
        float ang = freqs[pos * 64 + c];
        float sn, cs;
        __sincosf(ang, &sn, &cs);
        float2 gqa = g2q[p];
        float q0 = qv[j].x * scq * gqa.x, q1 = qv[j].y * scq * gqa.y;
        ushort2 oq; oq.x = f2bf(q0 * cs - q1 * sn); oq.y = f2bf(q0 * sn + q1 * cs);
        float2 gka = g2k[p];
        float kk0 = kv[j].x * sck * gka.x, kk1 = kv[j].y * sck * gka.y;
        ushort2 ok; ok.x = f2bf(kk0 * cs - kk1 * sn); ok.y = f2bf(kk0 * sn + kk1 * cs);
        int h = p >> 6;
        size_t off = ((size_t)h * SPADN + s) * HD + 2 * c;
        *(ushort2*)(Qa + off) = oq;
        *(ushort2*)(Ka + off) = ok;
    }
}

// ---------------- flash attention pass 1: split-K partials -----------------
// q128 tiles (wave = 32 q rows, 2 m-frags). Fixed-base softmax (no max, no
// shuffles), row-sum via ones-MFMA. K/V via global_load_lds, xor-swizzled.
// Single-chunk tiles (j<=3) normalize and write Ob directly (skip combine).
__global__ __launch_bounds__(256, 3) void k_attn1(const unsigned short* __restrict__ Qa,
                                                  const unsigned short* __restrict__ Ka,
                                                  const unsigned short* __restrict__ Vt,
                                                  unsigned short* __restrict__ Opart,
                                                  float* __restrict__ Lpart,
                                                  unsigned short* __restrict__ Ob) {
    int j = blockIdx.x, h = blockIdx.y, z = blockIdx.z;
    int nkb = 2 * j + 2;
    if (nkb > 33) nkb = 33;               // kb 33 fully padded -> skipped
    int nc = (nkb + 7) >> 3;
    if (z >= nc) return;
    int kb0 = z * 8;
    int kb1 = kb0 + 8; if (kb1 > nkb) kb1 = nkb;

    __shared__ unsigned short Ks[64 * 128];    // [key][d], xor-swizzled 16B chunks
    __shared__ unsigned short Vs[128 * 64];    // [d][key], xor-swizzled
    __shared__ unsigned short Ps[4][32][72];   // per-wave P round-trip (+8 pad)

    int tid = threadIdx.x;
    int lane = tid & 63, wv = tid >> 6;
    int quad = lane >> 4, l16 = lane & 15;
    int qrow0 = j * 128 + wv * 32;

    short8 qf[2][4];
#pragma unroll
    for (int mi = 0; mi < 2; mi++)
#pragma unroll
        for (int kc = 0; kc < 4; kc++)
            qf[mi][kc] = *(const short8*)(Qa + ((size_t)h * SPADN + qrow0 + mi * 16 + l16) * HD + kc * 32 + quad * 8);

    short8 ones8;
#pragma unroll
    for (int i = 0; i < 8; i++) ones8[i] = (short)0x3F80;   // bf16 1.0

    floatx4 of[2][8], of9[2];
#pragma unroll
    for (int mi = 0; mi < 2; mi++) {
#pragma unroll
        for (int ni = 0; ni < 8; ni++) of[mi][ni] = (floatx4){0.f, 0.f, 0.f, 0.f};
        of9[mi] = (floatx4){0.f, 0.f, 0.f, 0.f};
    }

    int krow = lane >> 4;        // Ks staging: 4 rows per wave-call
    int kslot = lane & 15;
    int vrow = lane >> 3;        // Vs staging: 8 rows per wave-call
    int vslot = lane & 7;

    for (int kb = kb0; kb < kb1; kb++) {
        const unsigned short* kbase = Ka + (((size_t)h * SPADN + kb * 64) * HD);
#pragma unroll
        for (int i = 0; i < 4; i++) {
            int rb = i * 4 + wv;                 // wave-uniform group of 4 K-rows
            int r = rb * 4 + krow;
            int g = (kslot & 8) | ((kslot & 7) ^ (r & 7));
            gld_lds16(kbase + r * 128 + g * 8, &Ks[rb * 512]);
        }
#pragma unroll
        for (int i = 0; i < 4; i++) {
            int rb = i * 4 + wv;                 // wave-uniform group of 8 V-rows
            int r = rb * 8 + vrow;
            int g = vslot ^ (r & 7);
            gld_lds16(Vt + ((size_t)h * HD + r) * SPADN + kb * 64 + g * 8, &Vs[rb * 512]);
        }
        __syncthreads();

        floatx4 sa[2][4];
#pragma unroll
        for (int mi = 0; mi < 2; mi++)
#pragma unroll
            for (int ni = 0; ni < 4; ni++) sa[mi][ni] = (floatx4){0.f, 0.f, 0.f, 0.f};
#pragma unroll
        for (int kc = 0; kc < 4; kc++) {
            int c = kc * 4 + quad;
            short8 kf[4];
#pragma unroll
            for (int ni = 0; ni < 4; ni++) {
                int row = ni * 16 + l16;
                int slot = (c & 8) | ((c & 7) ^ (row & 7));
                kf[ni] = *(const short8*)&Ks[row * 128 + slot * 8];
            }
#pragma unroll
            for (int mi = 0; mi < 2; mi++)
#pragma unroll
                for (int ni = 0; ni < 4; ni++)
                    sa[mi][ni] = __builtin_amdgcn_mfma_f32_16x16x32_bf16(qf[mi][kc], kf[ni], sa[mi][ni], 0, 0, 0);
        }

        bool maskb = (kb == 32);
#pragma unroll
        for (int mi = 0; mi < 2; mi++) {
#pragma unroll
            for (int r = 0; r < 4; r++) {
#pragma unroll
                for (int ni = 0; ni < 4; ni++) {
                    float xv = sa[mi][ni][r] * K2F;
                    if (maskb && (kb * 64 + ni * 16 + l16 >= SEQ)) xv = -1e30f;
                    float p = exp2f(fminf(xv, 36.f));
                    Ps[wv][mi * 16 + quad * 4 + r][ni * 16 + l16] = f2bf(p);
                }
            }
        }
        // PV (Ps wave-private: no barrier; same-wave LDS ordering suffices)
#pragma unroll
        for (int kc = 0; kc < 2; kc++) {
            int ko = kc * 32 + quad * 8;
            int c = kc * 4 + quad;
            short8 pf[2];
#pragma unroll
            for (int mi = 0; mi < 2; mi++) pf[mi] = *(const short8*)&Ps[wv][mi * 16 + l16][ko];
#pragma unroll
            for (int ni = 0; ni < 8; ni++) {
                int row = ni * 16 + l16;
                short8 vf = *(const short8*)&Vs[row * 64 + ((c ^ (row & 7)) << 3)];
#pragma unroll
                for (int mi = 0; mi < 2; mi++)
                    of[mi][ni] = __builtin_amdgcn_mfma_f32_16x16x32_bf16(pf[mi], vf, of[mi][ni], 0, 0, 0);
            }
#pragma unroll
            for (int mi = 0; mi < 2; mi++)
                of9[mi] = __builtin_amdgcn_mfma_f32_16x16x32_bf16(pf[mi], ones8, of9[mi], 0, 0, 0);
        }
        __syncthreads();
    }

    if (nc == 1) {
        // single chunk: normalize and write final output directly
#pragma unroll
        for (int mi = 0; mi < 2; mi++) {
#pragma unroll
            for (int r = 0; r < 4; r++) {
                float inv = 1.f / of9[mi][r];
                int row = qrow0 + mi * 16 + quad * 4 + r;   // j<=3 -> always < SEQ
#pragma unroll
                for (int ni = 0; ni < 8; ni++)
                    Ob[(size_t)row * DIMM + h * HD + ni * 16 + l16] = f2bf(of[mi][ni][r] * inv);
            }
        }
    } else {
        int slot = h * SLOTS2_PER_HEAD + c_base2[j] + z;
        unsigned short* Op = Opart + (size_t)slot * 16384;
#pragma unroll
        for (int mi = 0; mi < 2; mi++) {
#pragma unroll
            for (int r = 0; r < 4; r++) {
                int lrow = wv * 32 + mi * 16 + quad * 4 + r;
#pragma unroll
                for (int ni = 0; ni < 8; ni++)
                    Op[lrow * 128 + ni * 16 + l16] = f2bf(of[mi][ni][r]);
            }
        }
        if (l16 == 0) {
#pragma unroll
            for (int mi = 0; mi < 2; mi++)
#pragma unroll
                for (int r = 0; r < 4; r++)
                    Lpart[slot * 128 + wv * 32 + mi * 16 + quad * 4 + r] = of9[mi][r];
        }
    }
}

// ---------------- flash attention pass 2: combine partials (j>=4) ----------
__global__ void k_attn2(const unsigned short* __restrict__ Opart,
                        const float* __restrict__ Lpart,
                        unsigned short* __restrict__ Ob) {
    int j = blockIdx.x, h = blockIdx.y;
    int nkb = 2 * j + 2; if (nkb > 33) nkb = 33;
    int nc = (nkb + 7) >> 3;
    if (nc == 1) return;                 // attn1 wrote these directly
    int base = h * SLOTS2_PER_HEAD + c_base2[j];
    int t = threadIdx.x;
    int row = t >> 1;                    // 0..127
    int dh = (t & 1) * 64;
    int grow = j * 128 + row;
    if (grow >= SEQ) return;

    float acc[64];
#pragma unroll
    for (int q = 0; q < 64; q++) acc[q] = 0.f;
    float L = 0.f;
    for (int c = 0; c < nc; c++) {
        int slot = base + c;
        L += Lpart[slot * 128 + row];
        const ushort4* op = (const ushort4*)(Opart + (size_t)slot * 16384 + row * 128 + dh);
#pragma unroll
        for (int q = 0; q < 16; q++) {
            ushort4 u = op[q];
            acc[q * 4 + 0] += bf2f(u.x); acc[q * 4 + 1] += bf2f(u.y);
            acc[q * 4 + 2] += bf2f(u.z); acc[q * 4 + 3] += bf2f(u.w);
        }
    }
    float inv = 1.f / L;
    unsigned short* ob = Ob + (size_t)grow * DIMM + h * HD + dh;
#pragma unroll
    for (int q = 0; q < 16; q++) {
        ushort4 o;
        o.x = f2bf(acc[q * 4 + 0] * inv); o.y = f2bf(acc[q * 4 + 1] * inv);
        o.z = f2bf(acc[q * 4 + 2] * inv); o.w = f2bf(acc[q * 4 + 3] * inv);
        *(ushort4*)(ob + q * 4) = o;
    }
}

// ---------------------------------------------------------------------------
extern "C" void kernel_launch(void* const* d_in, const int* in_sizes, int n_in,
                              void* d_out, int out_size, void* d_ws, size_t ws_size,
                              hipStream_t stream) {
    const float* x     = (const float*)d_in[0];
    const float* freqs = (const float*)d_in[1];
    const float* wq    = (const float*)d_in[2];
    const float* bq    = (const float*)d_in[3];
    const float* wk    = (const float*)d_in[4];
    const float* bk    = (const float*)d_in[5];
    const float* wv    = (const float*)d_in[6];
    const float* bv    = (const float*)d_in[7];
    const float* wo    = (const float*)d_in[8];
    const float* bo    = (const float*)d_in[9];
    const float* gq    = (const float*)d_in[10];
    const float* gk    = (const float*)d_in[11];
    float* out = (float*)d_out;

    char* ws = (char*)d_ws;
    size_t off = 0;
    auto alloc = [&](size_t bytes) -> void* {
        void* p = ws + off;
        off += (bytes + 255) & ~(size_t)255;
        return p;
    };
    // Prefix buffers (dead before attn1) — Opart aliases them:
    //   xb (padded) 6.68 + wqT/wkT/wvT 14.16 + Qh/Kh 12.78 = 33.62 MB
    //   Opart (bf16) needs 12*45*128*128*2B = 17.7 MB  ✓
    unsigned short* xb  = (unsigned short*)alloc((size_t)SPADN * DIMM * 2);
    unsigned short* wqT = (unsigned short*)alloc((size_t)DIMM * DIMM * 2);
    unsigned short* wkT = (unsigned short*)alloc((size_t)DIMM * DIMM * 2);
    unsigned short* wvT = (unsigned short*)alloc((size_t)DIMM * DIMM * 2);
    unsigned short* Qh  = (unsigned short*)alloc((size_t)SEQ * DIMM * 2);
    unsigned short* Kh  = (unsigned short*)alloc((size_t)SEQ * DIMM * 2);
    // Live-late buffers (must NOT overlap Opart):
    unsigned short* woT = (unsigned short*)alloc((size_t)DIMM * DIMM * 2);
    unsigned short* Qa  = (unsigned short*)alloc((size_t)NHEAD * SPADN * HD * 2);
    unsigned short* Ka  = (unsigned short*)alloc((size_t)NHEAD * SPADN * HD * 2);
    unsigned short* Vt  = (unsigned short*)alloc((size_t)DIMM * SPADN * 2);
    unsigned short* Ob  = (unsigned short*)alloc((size_t)SEQ * DIMM * 2);
    float* Lpart = (float*)alloc((size_t)12 * SLOTS2_PER_HEAD * 128 * 4);
    unsigned short* Opart = (unsigned short*)ws;   // aliases prefix (dead by attn1)
    (void)ws_size; (void)in_sizes; (void)n_in; (void)out_size;

    // 1) prep: x->bf16 + 4 weight transposes (one launch)
    k_prep<<<dim3(24, 24, 5), 256, 0, stream>>>(x, wq, wk, wv, wo, xb, wqT, wkT, wvT, woT);
    // 2) QKV projections (+bias), bf16 outputs; z=2 writes Vt transposed
    k_gemm<<<dim3(12, 17, 3), 256, 0, stream>>>(xb, wqT, wkT, wvT, bq, bk, bv,
                                                Qh, Kh, Vt, SEQ, DIMM, DIMM);
    // 3) RMS + RoPE -> bf16 [h][s][d]   (consumes Qh, Kh)
    k_rmsrope<<<SEQ, 256, 0, stream>>>(Qh, Kh, gq, gk, freqs, Qa, Ka);
    // 4) attention: q128 split-K partials (bf16), then combine (j>=4 only)
    k_attn1<<<dim3(17, 12, 5), 256, 0, stream>>>(Qa, Ka, Vt, Opart, Lpart, Ob);
    k_attn2<<<dim3(17, 12), 256, 0, stream>>>(Opart, Lpart, Ob);
    // 5) output projection (+bo) -> d_out fp32, 64x64 tiles for occupancy
    k_gemm64<<<dim3(24, 33), 256, 0, stream>>>(Ob, woT, bo, out, SEQ, DIMM, DIMM);
}

// Round 7
// 235.576 us; speedup vs baseline: 1.1521x; 1.1521x over previous
//
#include <hip/hip_runtime.h>

// ---------------- problem constants (from reference setup_inputs) ----------
#define DIMM   1536
#define NHEAD  12
#define HD     128
#define SEQ    2080      // F*H*W = 4*20*26
#define SPADN  2176      // ceil(S/128)*128
#define HWPROD 520       // H*W
#define SCALE  0.08838834764831845f      // 1/sqrt(128)
#define K2F    0.12751744154f            // SCALE * log2(e)

typedef short short8  __attribute__((ext_vector_type(8)));   // 8 bf16 in 4 VGPRs
typedef float floatx4 __attribute__((ext_vector_type(4)));

__device__ __forceinline__ unsigned short f2bf(float f) {
    union { float f; unsigned u; } v; v.f = f;
    return (unsigned short)((v.u + 0x7fffu + ((v.u >> 16) & 1u)) >> 16);  // RNE
}
__device__ __forceinline__ float bf2f(unsigned short u) {
    union { unsigned u; float f; } v; v.u = ((unsigned)u) << 16;
    return v.f;
}

// async global->LDS, 16B per lane; LDS dest = wave-uniform base + lane*16
__device__ __forceinline__ void gld_lds16(const void* g, void* l) {
    __builtin_amdgcn_global_load_lds(
        (const __attribute__((address_space(1))) unsigned int*)g,
        (__attribute__((address_space(3))) unsigned int*)l, 16, 0, 0);
}

// q64 tiles: j=0..32, nkb(j)=min((j>>1)*2+2,33), nchunks=ceil(nkb/8).
// c_base = prefix sum of nchunks.  j<=7 -> single chunk (direct write).
__constant__ int c_base[33] = {0,1,2,3,4,5,6,7,
                               8,10,12,14,16,18,20,22,
                               24,27,30,33,36,39,42,45,
                               48,52,56,60,64,68,72,76,
                               80};
#define SLOTS_PER_HEAD 85

// ---------------- prep: x->bf16 (z=4) + 4 weight transposes (z=0..3) -------
__global__ void k_prep(const float* __restrict__ x,
                       const float* __restrict__ w0, const float* __restrict__ w1,
                       const float* __restrict__ w2, const float* __restrict__ w3,
                       unsigned short* __restrict__ xb,
                       unsigned short* __restrict__ t0, unsigned short* __restrict__ t1,
                       unsigned short* __restrict__ t2, unsigned short* __restrict__ t3) {
    int z = blockIdx.z;
    if (z == 4) {                       // cvt x: 2080*1536/4 float4 groups
        int n4 = SEQ * DIMM / 4;
        int idx = (blockIdx.y * 24 + blockIdx.x) * 256 + threadIdx.x;
#pragma unroll
        for (int i = 0; i < 6; i++) {
            int p = idx + i * 147456;
            if (p < n4) {
                float4 v = ((const float4*)x)[p];
                ushort4 o;
                o.x = f2bf(v.x); o.y = f2bf(v.y); o.z = f2bf(v.z); o.w = f2bf(v.w);
                ((ushort4*)xb)[p] = o;
            }
        }
        return;
    }
    const float* in = (z == 0) ? w0 : (z == 1) ? w1 : (z == 2) ? w2 : w3;
    unsigned short* out = (z == 0) ? t0 : (z == 1) ? t1 : (z == 2) ? t2 : t3;
    __shared__ float tile[64][65];
    int tx = threadIdx.x & 63, ty = threadIdx.x >> 6;
    int r0 = blockIdx.x * 64, c0 = blockIdx.y * 64;
#pragma unroll
    for (int i = 0; i < 16; i++)
        tile[i * 4 + ty][tx] = in[(size_t)(r0 + i * 4 + ty) * DIMM + c0 + tx];
    __syncthreads();
#pragma unroll
    for (int i = 0; i < 16; i++) {
        int cc = i * 4 + ty;
        out[(size_t)(c0 + cc) * DIMM + r0 + tx] = f2bf(tile[tx][cc]);
    }
}

// ---------------- QKV GEMM: bf16 out, fused layouts ------------------------
// 128x128 tile, BK=64, global_load_lds staging, xor-swizzled unpadded LDS.
// z=0 -> Qh bf16 [s][1536]; z=1 -> Kh bf16 [s][1536];
// z=2 -> Vt bf16 [1536][SPADN] (transposed store, pad cols left untouched).
__global__ __launch_bounds__(256, 3) void k_gemm(
    const unsigned short* __restrict__ A,
    const unsigned short* __restrict__ B0, const unsigned short* __restrict__ B1,
    const unsigned short* __restrict__ B2,
    const float* __restrict__ bias0, const float* __restrict__ bias1, const float* __restrict__ bias2,
    unsigned short* __restrict__ Qh, unsigned short* __restrict__ Kh,
    unsigned short* __restrict__ Vt,
    int M, int N, int K) {
    const unsigned short* B = B0; const float* bias = bias0;
    if (blockIdx.z == 1) { B = B1; bias = bias1; }
    if (blockIdx.z == 2) { B = B2; bias = bias2; }

    __shared__ unsigned short As[128 * 64];
    __shared__ unsigned short Bs[128 * 64];

    int tid = threadIdx.x;
    int lane = tid & 63, wv = tid >> 6;
    int quad = lane >> 4, l16 = lane & 15;
    int m0 = blockIdx.y * 128, n0 = blockIdx.x * 128;
    int wm = (wv >> 1) * 64, wn = (wv & 1) * 64;
    int sw = l16 & 7;

    int srow_in_blk = lane >> 3;
    int schunk = lane & 7;
    int gchunk = schunk ^ (srow_in_blk & 7);

    floatx4 acc[4][4];
#pragma unroll
    for (int i = 0; i < 4; i++)
#pragma unroll
        for (int j = 0; j < 4; j++) acc[i][j] = (floatx4){0.f, 0.f, 0.f, 0.f};

    for (int k0 = 0; k0 < K; k0 += 64) {
#pragma unroll
        for (int i = 0; i < 4; i++) {
            int blkrow = (wv * 4 + i) * 8;
            int r = blkrow + srow_in_blk;
            int ra = m0 + r; if (ra > M - 1) ra = M - 1;
            gld_lds16(A + (size_t)ra * K + k0 + gchunk * 8, &As[blkrow * 64]);
            gld_lds16(B + (size_t)(n0 + r) * K + k0 + gchunk * 8, &Bs[blkrow * 64]);
        }
        __syncthreads();
#pragma unroll
        for (int kc = 0; kc < 2; kc++) {
            short8 af[4], bfr[4];
#pragma unroll
            for (int t = 0; t < 4; t++) {
                int ca = ((kc * 4 + quad) ^ sw) << 3;
                af[t]  = *(const short8*)&As[(wm + t * 16 + l16) * 64 + ca];
                bfr[t] = *(const short8*)&Bs[(wn + t * 16 + l16) * 64 + ca];
            }
#pragma unroll
            for (int mi = 0; mi < 4; mi++)
#pragma unroll
                for (int ni = 0; ni < 4; ni++)
                    acc[mi][ni] = __builtin_amdgcn_mfma_f32_16x16x32_bf16(af[mi], bfr[ni], acc[mi][ni], 0, 0, 0);
        }
        __syncthreads();
    }
    // epilogue: C/D layout col=lane&15, row=quad*4+reg
    if (blockIdx.z == 2) {
        // Vt[d][q] transposed: rows r=0..3 are contiguous q indices per lane
#pragma unroll
        for (int mi = 0; mi < 4; mi++) {
            int row0 = m0 + wm + mi * 16 + quad * 4;
            if (row0 < M) {
#pragma unroll
                for (int ni = 0; ni < 4; ni++) {
                    int col = n0 + wn + ni * 16 + l16;
                    float b = bias[col];
                    ushort4 o;
                    o.x = f2bf(acc[mi][ni][0] + b);
                    o.y = f2bf(acc[mi][ni][1] + b);
                    o.z = f2bf(acc[mi][ni][2] + b);
                    o.w = f2bf(acc[mi][ni][3] + b);
                    *(ushort4*)(Vt + (size_t)col * SPADN + row0) = o;
                }
            }
        }
    } else {
        unsigned short* O = (blockIdx.z == 0) ? Qh : Kh;
#pragma unroll
        for (int mi = 0; mi < 4; mi++) {
#pragma unroll
            for (int r = 0; r < 4; r++) {
                int row = m0 + wm + mi * 16 + quad * 4 + r;
                if (row < M) {
#pragma unroll
                    for (int ni = 0; ni < 4; ni++) {
                        int col = n0 + wn + ni * 16 + l16;
                        O[(size_t)row * DIMM + col] = f2bf(acc[mi][ni][r] + bias[col]);
                    }
                }
            }
        }
    }
}

// ---------------- 64x64-tile GEMM for the output projection ---------------
__global__ __launch_bounds__(256, 8) void k_gemm64(
    const unsigned short* __restrict__ A, const unsigned short* __restrict__ B,
    const float* __restrict__ bias, float* __restrict__ C, int M, int N, int K) {
    __shared__ unsigned short As[64 * 64];
    __shared__ unsigned short Bs[64 * 64];
    int tid = threadIdx.x;
    int lane = tid & 63, wv = tid >> 6;
    int quad = lane >> 4, l16 = lane & 15;
    int m0 = blockIdx.y * 64, n0 = blockIdx.x * 64;
    int wm = (wv >> 1) * 32, wn = (wv & 1) * 32;

    int srow = lane >> 3;       // 0..7 rows per wave-call
    int schunk = lane & 7;

    floatx4 acc[2][2];
#pragma unroll
    for (int i = 0; i < 2; i++)
#pragma unroll
        for (int j = 0; j < 2; j++) acc[i][j] = (floatx4){0.f, 0.f, 0.f, 0.f};

    for (int k0 = 0; k0 < K; k0 += 64) {
#pragma unroll
        for (int i = 0; i < 2; i++) {
            int rb = (i * 4 + wv) * 8;            // wave-uniform row base
            int r = rb + srow;
            int g = schunk ^ (r & 7);
            int ra = m0 + r; if (ra > M - 1) ra = M - 1;
            gld_lds16(A + (size_t)ra * K + k0 + g * 8, &As[rb * 64]);
            gld_lds16(B + (size_t)(n0 + r) * K + k0 + g * 8, &Bs[rb * 64]);
        }
        __syncthreads();
#pragma unroll
        for (int kc = 0; kc < 2; kc++) {
            short8 af[2], bfr[2];
#pragma unroll
            for (int t = 0; t < 2; t++) {
                int rowa = wm + t * 16 + l16;
                int rowb = wn + t * 16 + l16;
                int c = kc * 4 + quad;
                af[t]  = *(const short8*)&As[rowa * 64 + ((c ^ (rowa & 7)) << 3)];
                bfr[t] = *(const short8*)&Bs[rowb * 64 + ((c ^ (rowb & 7)) << 3)];
            }
#pragma unroll
            for (int mi = 0; mi < 2; mi++)
#pragma unroll
                for (int ni = 0; ni < 2; ni++)
                    acc[mi][ni] = __builtin_amdgcn_mfma_f32_16x16x32_bf16(af[mi], bfr[ni], acc[mi][ni], 0, 0, 0);
        }
        __syncthreads();
    }
#pragma unroll
    for (int mi = 0; mi < 2; mi++) {
#pragma unroll
        for (int r = 0; r < 4; r++) {
            int row = m0 + wm + mi * 16 + quad * 4 + r;
            if (row < M) {
#pragma unroll
                for (int ni = 0; ni < 2; ni++) {
                    int col = n0 + wn + ni * 16 + l16;
                    C[(size_t)row * N + col] = acc[mi][ni][r] + bias[col];
                }
            }
        }
    }
}

// ---------------- RMSNorm(1536) + RoPE (bf16 in), write bf16 [h][s][d] -----
__global__ void k_rmsrope(const unsigned short* __restrict__ Qh, const unsigned short* __restrict__ Kh,
                          const float* __restrict__ gq, const float* __restrict__ gk,
                          const float* __restrict__ freqs,
                          unsigned short* __restrict__ Qa, unsigned short* __restrict__ Ka) {
    __shared__ float redq[4], redk[4];
    int s = blockIdx.x;
    int tid = threadIdx.x;
    int lane = tid & 63, wv = tid >> 6;
    const ushort2* qrow = (const ushort2*)(Qh + (size_t)s * DIMM);
    const ushort2* krow = (const ushort2*)(Kh + (size_t)s * DIMM);
    const float2* g2q = (const float2*)gq;
    const float2* g2k = (const float2*)gk;

    float2 qv[3], kv[3];
    float sq = 0.f, sk = 0.f;
#pragma unroll
    for (int j = 0; j < 3; j++) {
        int p = tid + j * 256;
        ushort2 uq = qrow[p], uk = krow[p];
        qv[j].x = bf2f(uq.x); qv[j].y = bf2f(uq.y);
        kv[j].x = bf2f(uk.x); kv[j].y = bf2f(uk.y);
        sq += qv[j].x * qv[j].x + qv[j].y * qv[j].y;
        sk += kv[j].x * kv[j].x + kv[j].y * kv[j].y;
    }
#pragma unroll
    for (int m = 32; m >= 1; m >>= 1) { sq += __shfl_xor(sq, m); sk += __shfl_xor(sk, m); }
    if (lane == 0) { redq[wv] = sq; redk[wv] = sk; }
    __syncthreads();
    float tq = redq[0] + redq[1] + redq[2] + redq[3];
    float tk = redk[0] + redk[1] + redk[2] + redk[3];
    float scq = rsqrtf(tq * (1.f / DIMM) + 1e-6f);
    float sck = rsqrtf(tk * (1.f / DIMM) + 1e-6f);

    int fi = s / HWPROD;
    int rem = s - fi * HWPROD;
    int hi = rem / 26;
    int wi = rem - hi * 26;
#pragma unroll
    for (int j = 0; j < 3; j++) {
        int p = tid + j * 256;
        int c = p & 63;
        int pos = (c < 22) ? fi : ((c < 43) ? hi : wi);
        float ang = freqs[pos * 64 + c];
        float sn, cs;
        __sincosf(ang, &sn, &cs);
        float2 gqa = g2q[p];
        float q0 = qv[j].x * scq * gqa.x, q1 = qv[j].y * scq * gqa.y;
        ushort2 oq; oq.x = f2bf(q0 * cs - q1 * sn); oq.y = f2bf(q0 * sn + q1 * cs);
        float2 gka = g2k[p];
        float kk0 = kv[j].x * sck * gka.x, kk1 = kv[j].y * sck * gka.y;
        ushort2 ok; ok.x = f2bf(kk0 * cs - kk1 * sn); ok.y = f2bf(kk0 * sn + kk1 * cs);
        int h = p >> 6;
        size_t off = ((size_t)h * SPADN + s) * HD + 2 * c;
        *(ushort2*)(Qa + off) = oq;
        *(ushort2*)(Ka + off) = ok;
    }
}

// ---------------- flash attention pass 1: split-K partials (q64) -----------
// Fixed-base softmax (no max, no shuffles), row-sum via ones-MFMA.
// K/V via global_load_lds into xor-swizzled unpadded LDS.
// Single-chunk tiles (j<=7) normalize and write Ob directly (skip combine).
__global__ __launch_bounds__(256, 3) void k_attn1(const unsigned short* __restrict__ Qa,
                                                  const unsigned short* __restrict__ Ka,
                                                  const unsigned short* __restrict__ Vt,
                                                  unsigned short* __restrict__ Opart,
                                                  float* __restrict__ Lpart,
                                                  unsigned short* __restrict__ Ob) {
    int j = blockIdx.x, h = blockIdx.y, z = blockIdx.z;
    int nkb = (j >> 1) * 2 + 2;
    if (nkb > 33) nkb = 33;               // kb 33 fully padded -> skipped
    int nc = (nkb + 7) >> 3;
    if (z >= nc) return;
    int kb0 = z * 8;
    int kb1 = kb0 + 8; if (kb1 > nkb) kb1 = nkb;

    __shared__ unsigned short Ks[64 * 128];    // [key][d], xor-swizzled 16B chunks
    __shared__ unsigned short Vs[128 * 64];    // [d][key], xor-swizzled
    __shared__ unsigned short Ps[4][16][72];   // per-wave P round-trip (+8 pad)

    int tid = threadIdx.x;
    int lane = tid & 63, wv = tid >> 6;
    int quad = lane >> 4, l16 = lane & 15;
    int qrow0 = j * 64 + wv * 16;

    short8 qf[4];
#pragma unroll
    for (int kc = 0; kc < 4; kc++)
        qf[kc] = *(const short8*)(Qa + ((size_t)h * SPADN + qrow0 + l16) * HD + kc * 32 + quad * 8);

    short8 ones8;
#pragma unroll
    for (int i = 0; i < 8; i++) ones8[i] = (short)0x3F80;   // bf16 1.0

    floatx4 of[8], of9;
#pragma unroll
    for (int ni = 0; ni < 8; ni++) of[ni] = (floatx4){0.f, 0.f, 0.f, 0.f};
    of9 = (floatx4){0.f, 0.f, 0.f, 0.f};

    int krow = lane >> 4;        // Ks staging: 4 rows per wave-call
    int kslot = lane & 15;
    int vrow = lane >> 3;        // Vs staging: 8 rows per wave-call
    int vslot = lane & 7;

    for (int kb = kb0; kb < kb1; kb++) {
        const unsigned short* kbase = Ka + (((size_t)h * SPADN + kb * 64) * HD);
#pragma unroll
        for (int i = 0; i < 4; i++) {
            int rb = i * 4 + wv;                 // wave-uniform group of 4 K-rows
            int r = rb * 4 + krow;
            int g = (kslot & 8) | ((kslot & 7) ^ (r & 7));
            gld_lds16(kbase + r * 128 + g * 8, &Ks[rb * 512]);
        }
#pragma unroll
        for (int i = 0; i < 4; i++) {
            int rb = i * 4 + wv;                 // wave-uniform group of 8 V-rows
            int r = rb * 8 + vrow;
            int g = vslot ^ (r & 7);
            gld_lds16(Vt + ((size_t)h * HD + r) * SPADN + kb * 64 + g * 8, &Vs[rb * 512]);
        }
        __syncthreads();

        floatx4 sa[4];
#pragma unroll
        for (int ni = 0; ni < 4; ni++) sa[ni] = (floatx4){0.f, 0.f, 0.f, 0.f};
#pragma unroll
        for (int kc = 0; kc < 4; kc++) {
            int c = kc * 4 + quad;
            short8 kf[4];
#pragma unroll
            for (int ni = 0; ni < 4; ni++) {
                int row = ni * 16 + l16;
                int slot = (c & 8) | ((c & 7) ^ (row & 7));
                kf[ni] = *(const short8*)&Ks[row * 128 + slot * 8];
            }
#pragma unroll
            for (int ni = 0; ni < 4; ni++)
                sa[ni] = __builtin_amdgcn_mfma_f32_16x16x32_bf16(qf[kc], kf[ni], sa[ni], 0, 0, 0);
        }

        bool maskb = (kb == 32);
#pragma unroll
        for (int r = 0; r < 4; r++) {
#pragma unroll
            for (int ni = 0; ni < 4; ni++) {
                float xv = sa[ni][r] * K2F;
                if (maskb && (kb * 64 + ni * 16 + l16 >= SEQ)) xv = -1e30f;
                float p = exp2f(fminf(xv, 36.f));
                Ps[wv][quad * 4 + r][ni * 16 + l16] = f2bf(p);
            }
        }
        // PV (Ps wave-private: no barrier; same-wave LDS ordering suffices)
#pragma unroll
        for (int kc = 0; kc < 2; kc++) {
            int ko = kc * 32 + quad * 8;
            int c = kc * 4 + quad;
            short8 pf = *(const short8*)&Ps[wv][l16][ko];
#pragma unroll
            for (int ni = 0; ni < 8; ni++) {
                int row = ni * 16 + l16;
                short8 vf = *(const short8*)&Vs[row * 64 + ((c ^ (row & 7)) << 3)];
                of[ni] = __builtin_amdgcn_mfma_f32_16x16x32_bf16(pf, vf, of[ni], 0, 0, 0);
            }
            of9 = __builtin_amdgcn_mfma_f32_16x16x32_bf16(pf, ones8, of9, 0, 0, 0);
        }
        __syncthreads();
    }

    if (nc == 1) {
        // single chunk (j<=7): normalize and write final output directly
#pragma unroll
        for (int r = 0; r < 4; r++) {
            float inv = 1.f / of9[r];
            int row = qrow0 + quad * 4 + r;       // j<=7 -> always < SEQ
#pragma unroll
            for (int ni = 0; ni < 8; ni++)
                Ob[(size_t)row * DIMM + h * HD + ni * 16 + l16] = f2bf(of[ni][r] * inv);
        }
    } else {
        int slot = h * SLOTS_PER_HEAD + c_base[j] + z;
        unsigned short* Op = Opart + (size_t)slot * 8192;
#pragma unroll
        for (int r = 0; r < 4; r++) {
            int lrow = wv * 16 + quad * 4 + r;
#pragma unroll
            for (int ni = 0; ni < 8; ni++)
                Op[lrow * 128 + ni * 16 + l16] = f2bf(of[ni][r]);
        }
        if (l16 == 0) {
#pragma unroll
            for (int r = 0; r < 4; r++)
                Lpart[slot * 64 + wv * 16 + quad * 4 + r] = of9[r];
        }
    }
}

// ---------------- flash attention pass 2: combine partials (j>=8) ----------
__global__ void k_attn2(const unsigned short* __restrict__ Opart,
                        const float* __restrict__ Lpart,
                        unsigned short* __restrict__ Ob) {
    int j = blockIdx.x, h = blockIdx.y;
    int nkb = (j >> 1) * 2 + 2; if (nkb > 33) nkb = 33;
    int nc = (nkb + 7) >> 3;
    if (nc == 1) return;                 // attn1 wrote these directly
    int base = h * SLOTS_PER_HEAD + c_base[j];
    int t = threadIdx.x;
    int r = t >> 2;                      // 0..63
    int c0 = (t & 3) * 32;
    int row = j * 64 + r;
    if (row >= SEQ) return;

    float acc[32];
#pragma unroll
    for (int q = 0; q < 32; q++) acc[q] = 0.f;
    float L = 0.f;
    for (int c = 0; c < nc; c++) {
        int slot = base + c;
        L += Lpart[slot * 64 + r];
        const ushort4* op = (const ushort4*)(Opart + (size_t)slot * 8192 + r * 128 + c0);
#pragma unroll
        for (int q = 0; q < 8; q++) {
            ushort4 u = op[q];
            acc[q * 4 + 0] += bf2f(u.x); acc[q * 4 + 1] += bf2f(u.y);
            acc[q * 4 + 2] += bf2f(u.z); acc[q * 4 + 3] += bf2f(u.w);
        }
    }
    float inv = 1.f / L;
    unsigned short* ob = Ob + (size_t)row * DIMM + h * HD + c0;
#pragma unroll
    for (int q = 0; q < 8; q++) {
        ushort4 o;
        o.x = f2bf(acc[q * 4 + 0] * inv); o.y = f2bf(acc[q * 4 + 1] * inv);
        o.z = f2bf(acc[q * 4 + 2] * inv); o.w = f2bf(acc[q * 4 + 3] * inv);
        *(ushort4*)(ob + q * 4) = o;
    }
}

// ---------------------------------------------------------------------------
extern "C" void kernel_launch(void* const* d_in, const int* in_sizes, int n_in,
                              void* d_out, int out_size, void* d_ws, size_t ws_size,
                              hipStream_t stream) {
    const float* x     = (const float*)d_in[0];
    const float* freqs = (const float*)d_in[1];
    const float* wq    = (const float*)d_in[2];
    const float* bq    = (const float*)d_in[3];
    const float* wk    = (const float*)d_in[4];
    const float* bk    = (const float*)d_in[5];
    const float* wv    = (const float*)d_in[6];
    const float* bv    = (const float*)d_in[7];
    const float* wo    = (const float*)d_in[8];
    const float* bo    = (const float*)d_in[9];
    const float* gq    = (const float*)d_in[10];
    const float* gk    = (const float*)d_in[11];
    float* out = (float*)d_out;

    char* ws = (char*)d_ws;
    size_t off = 0;
    auto alloc = [&](size_t bytes) -> void* {
        void* p = ws + off;
        off += (bytes + 255) & ~(size_t)255;
        return p;
    };
    // Prefix buffers (dead before attn1) — Opart aliases them:
    //   xb (padded) 6.68 + wqT/wkT/wvT 14.16 + Qh/Kh 12.78 = 33.62 MB
    //   Opart (bf16) needs 12*85*64*128*2B = 16.7 MB  ✓
    unsigned short* xb  = (unsigned short*)alloc((size_t)SPADN * DIMM * 2);
    unsigned short* wqT = (unsigned short*)alloc((size_t)DIMM * DIMM * 2);
    unsigned short* wkT = (unsigned short*)alloc((size_t)DIMM * DIMM * 2);
    unsigned short* wvT = (unsigned short*)alloc((size_t)DIMM * DIMM * 2);
    unsigned short* Qh  = (unsigned short*)alloc((size_t)SEQ * DIMM * 2);
    unsigned short* Kh  = (unsigned short*)alloc((size_t)SEQ * DIMM * 2);
    // Live-late buffers (must NOT overlap Opart):
    unsigned short* woT = (unsigned short*)alloc((size_t)DIMM * DIMM * 2);
    unsigned short* Qa  = (unsigned short*)alloc((size_t)NHEAD * SPADN * HD * 2);
    unsigned short* Ka  = (unsigned short*)alloc((size_t)NHEAD * SPADN * HD * 2);
    unsigned short* Vt  = (unsigned short*)alloc((size_t)DIMM * SPADN * 2);
    unsigned short* Ob  = (unsigned short*)alloc((size_t)SEQ * DIMM * 2);
    float* Lpart = (float*)alloc((size_t)12 * SLOTS_PER_HEAD * 64 * 4);
    unsigned short* Opart = (unsigned short*)ws;   // aliases prefix (dead by attn1)
    (void)ws_size; (void)in_sizes; (void)n_in; (void)out_size;

    // 1) prep: x->bf16 + 4 weight transposes (one launch)
    k_prep<<<dim3(24, 24, 5), 256, 0, stream>>>(x, wq, wk, wv, wo, xb, wqT, wkT, wvT, woT);
    // 2) QKV projections (+bias), bf16 outputs; z=2 writes Vt transposed
    k_gemm<<<dim3(12, 17, 3), 256, 0, stream>>>(xb, wqT, wkT, wvT, bq, bk, bv,
                                                Qh, Kh, Vt, SEQ, DIMM, DIMM);
    // 3) RMS + RoPE -> bf16 [h][s][d]   (consumes Qh, Kh)
    k_rmsrope<<<SEQ, 256, 0, stream>>>(Qh, Kh, gq, gk, freqs, Qa, Ka);
    // 4) attention: q64 split-K partials (bf16), then combine (j>=8 only)
    k_attn1<<<dim3(33, 12, 5), 256, 0, stream>>>(Qa, Ka, Vt, Opart, Lpart, Ob);
    k_attn2<<<dim3(33, 12), 256, 0, stream>>>(Opart, Lpart, Ob);
    // 5) output projection (+bo) -> d_out fp32, 64x64 tiles for occupancy
    k_gemm64<<<dim3(24, 33), 256, 0, stream>>>(Ob, woT, bo, out, SEQ, DIMM, DIMM);
}